// Round 3
// baseline (1288.133 us; speedup 1.0000x reference)
//
#include <hip/hip_runtime.h>

// Problem constants
constexpr int Bn  = 128;
constexpr int Tn  = 48000;
constexpr int NFn = 2999;   // fast frames
constexpr int NSn = 999;    // slow frames
constexpr int G3n = 192;    // 3*GH
constexpr int GHn = 64;

typedef float f2 __attribute__((ext_vector_type(2)));
typedef float f4 __attribute__((ext_vector_type(4)));

// ---------------------------------------------------------------------------
// Kernel 1: GI[b, t, j] = b_ih[j] + sum_{k<96} x[b, t*48+k] * W_ih[j, k]
// (unchanged — known-good, no spills)
// ---------------------------------------------------------------------------
__global__ __launch_bounds__(192) void gi_kernel(const float* __restrict__ x,
                                                 const float* __restrict__ W_ih,
                                                 const float* __restrict__ b_ih,
                                                 float* __restrict__ GI) {
  __shared__ __align__(16) float WT[48 * 196];   // [k][j] padded stride 196
  __shared__ float xs[1584];                     // 31*48+96 samples
  const int tile = blockIdx.x;        // 0..31
  const int b    = blockIdx.y;        // 0..127
  const int t0   = tile * 32;
  const int nt   = min(32, NSn - t0); // 32 or 7 (last tile)
  const int tid  = threadIdx.x;

  const int span = (nt - 1) * 48 + 96;
  for (int i = tid; i < 1584; i += 192)
    xs[i] = (i < span) ? x[(size_t)b * Tn + t0 * 48 + i] : 0.0f;

  const int jq = tid % 48;   // j-quad index
  const int tg = tid / 48;   // t-group (0..3)
  const int j0 = jq * 4;

  float acc[8][4];
#pragma unroll
  for (int u = 0; u < 8; ++u)
#pragma unroll
    for (int jj = 0; jj < 4; ++jj) acc[u][jj] = b_ih[j0 + jj];

  for (int half = 0; half < 2; ++half) {
    __syncthreads();
    for (int e = tid; e < 192 * 48; e += 192) {
      int j = e / 48, k = e % 48;
      WT[k * 196 + j] = W_ih[j * 96 + half * 48 + k];
    }
    __syncthreads();
    for (int k = 0; k < 48; ++k) {
      float4 w = *(const float4*)&WT[k * 196 + j0];
#pragma unroll
      for (int u = 0; u < 8; ++u) {
        float xv = xs[(tg * 8 + u) * 48 + half * 48 + k];
        acc[u][0] = fmaf(xv, w.x, acc[u][0]);
        acc[u][1] = fmaf(xv, w.y, acc[u][1]);
        acc[u][2] = fmaf(xv, w.z, acc[u][2]);
        acc[u][3] = fmaf(xv, w.w, acc[u][3]);
      }
    }
  }

#pragma unroll
  for (int u = 0; u < 8; ++u) {
    int tl = tg * 8 + u;
    if (tl < nt) {
      float4 st = make_float4(acc[u][0], acc[u][1], acc[u][2], acc[u][3]);
      *(float4*)&GI[(size_t)(b * NSn + t0 + tl) * G3n + j0] = st;
    }
  }
}

// ---------------------------------------------------------------------------
// Kernel 2: GRU, one wave per batch element — EXACT round-0 revert (485 us
// measured). Rounds 1-2 refuted both alternatives: (a) 2 waves/SIMD forces a
// 256-reg cap -> weight spills (730 us); (b) 4-wave k-split trades 288 cy of
// FMA issue for ~800 cy of barrier/LDS/readlane serial latency (703 us).
// Weight residency + single-wave step is the local optimum here.
// ---------------------------------------------------------------------------
__device__ __forceinline__ float fsigmoid(float v) {
  return __fdividef(1.0f, 1.0f + __expf(-v));
}
__device__ __forceinline__ float ftanh_f(float v) {
  return 1.0f - __fdividef(2.0f, __expf(2.0f * v) + 1.0f);
}

__global__ __attribute__((amdgpu_flat_work_group_size(64, 64),
                          amdgpu_waves_per_eu(1, 1),
                          amdgpu_num_vgpr(256)))
void gru_kernel(const float* __restrict__ GI,
                const float* __restrict__ W_hh,
                const float* __restrict__ b_hh,
                float* __restrict__ hs) {
  __shared__ __align__(16) float hbuf[64];
  const int b = blockIdx.x;
  const int j = threadIdx.x;

  f2 wr2[32], wz2[32], wn2[32];
  const f2* Wr = (const f2*)(W_hh + (size_t)j * 64);
  const f2* Wz = (const f2*)(W_hh + (size_t)(j + 64) * 64);
  const f2* Wn = (const f2*)(W_hh + (size_t)(j + 128) * 64);
#pragma unroll
  for (int q = 0; q < 32; ++q) { wr2[q] = Wr[q]; wz2[q] = Wz[q]; wn2[q] = Wn[q]; }
  // Opaque to the compiler => cannot re-load from memory inside the loop.
#pragma unroll
  for (int q = 0; q < 32; ++q) {
    asm volatile("" : "+v"(wr2[q]));
    asm volatile("" : "+v"(wz2[q]));
    asm volatile("" : "+v"(wn2[q]));
  }
  const float br = b_hh[j], bz = b_hh[j + 64], bn = b_hh[j + 128];

  hbuf[j] = 0.0f;
  float hj = 0.0f;
  __builtin_amdgcn_wave_barrier();

  const float* gp = GI + (size_t)b * NSn * G3n;
  float* hsp = hs + (size_t)b * NSn * GHn;

  // distance-2 prefetch ring (9 live regs; keeps total budget under 256)
  float pr0, pr1, pr2, pz0, pz1, pz2, pn0, pn1, pn2;
  pr0 = gp[0 * G3n + j];       pz0 = gp[0 * G3n + 64 + j];  pn0 = gp[0 * G3n + 128 + j];
  pr1 = gp[1 * G3n + j];       pz1 = gp[1 * G3n + 64 + j];  pn1 = gp[1 * G3n + 128 + j];

  for (int t = 0; t < NSn; ++t) {
    const size_t off = (size_t)min(t + 2, NSn - 1) * G3n;
    pr2 = gp[off + j];
    pz2 = gp[off + 64 + j];
    pn2 = gp[off + 128 + j];

    const f2* h2 = (const f2*)hbuf;
    f2 ar0 = {0.f, 0.f}, ar1 = {0.f, 0.f}, ar2 = {0.f, 0.f}, ar3 = {0.f, 0.f};
    f2 az0 = {0.f, 0.f}, az1 = {0.f, 0.f}, az2 = {0.f, 0.f}, az3 = {0.f, 0.f};
    f2 an0 = {0.f, 0.f}, an1 = {0.f, 0.f}, an2 = {0.f, 0.f}, an3 = {0.f, 0.f};
#pragma unroll
    for (int q = 0; q < 8; ++q) {
      f2 h0 = h2[q * 4 + 0], h1 = h2[q * 4 + 1], h2v = h2[q * 4 + 2], h3 = h2[q * 4 + 3];
      ar0 += wr2[q * 4 + 0] * h0; ar1 += wr2[q * 4 + 1] * h1;
      ar2 += wr2[q * 4 + 2] * h2v; ar3 += wr2[q * 4 + 3] * h3;
      az0 += wz2[q * 4 + 0] * h0; az1 += wz2[q * 4 + 1] * h1;
      az2 += wz2[q * 4 + 2] * h2v; az3 += wz2[q * 4 + 3] * h3;
      an0 += wn2[q * 4 + 0] * h0; an1 += wn2[q * 4 + 1] * h1;
      an2 += wn2[q * 4 + 2] * h2v; an3 += wn2[q * 4 + 3] * h3;
    }
    f2 sr = (ar0 + ar1) + (ar2 + ar3);
    f2 sz = (az0 + az1) + (az2 + az3);
    f2 sn = (an0 + an1) + (an2 + an3);

    float r = fsigmoid(pr0 + br + sr.x + sr.y);
    float z = fsigmoid(pz0 + bz + sz.x + sz.y);
    float n = ftanh_f(fmaf(r, bn + sn.x + sn.y, pn0));
    float hn = fmaf(z, hj - n, n);          // (1-z)*n + z*h

    // Pin ordering: reads of hbuf (above) before the write; write before
    // next iteration's reads. In-order per-wave DS pipe gives RAW safety.
    __builtin_amdgcn_wave_barrier();
    hbuf[j] = hn;
    __builtin_amdgcn_wave_barrier();
    hj = hn;
    hsp[(size_t)t * GHn + j] = hn;

    pr0 = pr1; pr1 = pr2;
    pz0 = pz1; pz1 = pz2;
    pn0 = pn1; pn1 = pn2;
  }
}

// ---------------------------------------------------------------------------
// Kernel 2b: cs[b, ts, i] = b_cs[i] + sum_k hs[b, ts, k] * W_cs[i, k]
// (unchanged)
// ---------------------------------------------------------------------------
__global__ __launch_bounds__(256) void cs_kernel(const float* __restrict__ hs,
                                                 const float* __restrict__ W_cs,
                                                 const float* __restrict__ b_cs,
                                                 float* __restrict__ cs) {
  __shared__ __align__(16) float WcT[64 * 36];  // [k][i] stride 36
  __shared__ __align__(16) float hsl[32 * 65];  // [t][k] stride 65
  __shared__ __align__(16) float bcs[32];
  const int tile = blockIdx.x;   // 0..31
  const int b    = blockIdx.y;
  const int t0   = tile * 32;
  const int nt   = min(32, NSn - t0);
  const int tid  = threadIdx.x;

  for (int e = tid; e < 32 * 64; e += 256) {
    int i = e >> 6, k = e & 63;
    WcT[k * 36 + i] = W_cs[e];
  }
  for (int e = tid; e < nt * 64; e += 256) {
    int t = e >> 6, k = e & 63;
    hsl[t * 65 + k] = hs[((size_t)b * NSn + t0 + t) * GHn + k];
  }
  if (tid < 32) bcs[tid] = b_cs[tid];
  __syncthreads();

  const int oq = tid & 7;    // output quad 0..7
  const int t  = tid >> 3;   // 0..31
  if (t < nt) {
    float4 acc = *(const float4*)&bcs[oq * 4];
    const float* hr = &hsl[t * 65];
#pragma unroll 4
    for (int k = 0; k < 64; ++k) {
      float hv = hr[k];
      float4 w = *(const float4*)&WcT[k * 36 + oq * 4];
      acc.x = fmaf(w.x, hv, acc.x);
      acc.y = fmaf(w.y, hv, acc.y);
      acc.z = fmaf(w.z, hv, acc.z);
      acc.w = fmaf(w.w, hv, acc.w);
    }
    *(float4*)&cs[((size_t)b * NSn + t0 + t) * 32 + oq * 4] = acc;
  }
}

// ---------------------------------------------------------------------------
// Kernel 3: fast MLP + overlap-add.
// REWRITTEN GEMM phases: the old version did one ds_read_b32 + one
// ds_read_b128 per 4 MACs (~675 KB LDS reads per block in compute1 alone)
// -> DS-pipe-bound, ~250-300 us across the 12032 blocks. Now each thread
// owns 4 output rows x one 32-wide k-half of W in REGISTERS (128 VGPRs,
// loaded once per block from global/L2) and streams A / h1 as b128
// broadcasts; k-halves combine through a small LDS partial buffer.
// Staging, yloc semantics and overlap-add are byte-identical to before.
// ---------------------------------------------------------------------------
__global__ __launch_bounds__(256, 1) void out_kernel(const float* __restrict__ x,
                                                     const float* __restrict__ cs,
                                                     const float* __restrict__ W1,
                                                     const float* __restrict__ b1,
                                                     const float* __restrict__ W2,
                                                     const float* __restrict__ b2,
                                                     float* __restrict__ out) {
  __shared__ __align__(16) float A[33 * 68];      // [lf][k] stride 68 (b128-aligned)
  __shared__ __align__(16) float P[2][33][64];    // k-half partials, compute1
  __shared__ __align__(16) float h1loc[33 * 68];  // [lf][o] stride 68
  __shared__ __align__(16) float P2[2][33][32];   // k-half partials, compute2
  __shared__ __align__(16) float yloc[33 * 32];
  __shared__ __align__(16) float bb1[64];
  __shared__ __align__(16) float bb2[32];

  const int fb  = blockIdx.x;
  const int b   = blockIdx.y;
  const int f0  = fb * 32;
  const int nf  = min(33, NFn - f0);
  const int tid = threadIdx.x;

  // ---- compute1 thread mapping: (oq, kh, lfp) ----
  const int oq  = tid & 15;        // output quad: outputs oq*4..oq*4+3
  const int kh  = (tid >> 4) & 1;  // k half: k in [kh*32, kh*32+32)
  const int lfp = tid >> 5;        // 0..7; covers lf = lfp + 8m

  // W1 rows for this thread's 4 outputs, this k-half: 128 VGPRs, from L2.
  f4 w1r[4][8];
#pragma unroll
  for (int r = 0; r < 4; ++r)
#pragma unroll
    for (int i = 0; i < 8; ++i)
      w1r[r][i] = *(const f4*)&W1[(size_t)(oq * 4 + r) * 64 + kh * 32 + 4 * i];

  if (tid < 64) bb1[tid] = b1[tid];
  if (tid < 32) bb2[tid] = b2[tid];

  for (int e = tid; e < 33 * 32; e += 256) {
    int lf = e >> 5, k = e & 31;
    int g = (f0 + lf) * 16 + k;
    A[lf * 68 + k] = (lf < nf && g < Tn) ? x[(size_t)b * Tn + g] : 0.0f;
  }
  for (int e = tid; e < 33 * 32; e += 256) {
    int lf = e >> 5, k = e & 31;
    int ts = max((f0 + lf) / 3 - 1, 0);
    A[lf * 68 + 32 + k] = (lf < nf) ? cs[((size_t)b * NSn + ts) * 32 + k] : 0.0f;
  }
  __syncthreads();

  // ---- compute1 partials: P[kh][lf][o] = sum over this k-half ----
#pragma unroll
  for (int m = 0; m < 5; ++m) {
    const int lf = lfp + 8 * m;
    if (lf < 33) {
      const f4* ar = (const f4*)&A[lf * 68 + kh * 32];
      f4 av[8];
#pragma unroll
      for (int i = 0; i < 8; ++i) av[i] = ar[i];
      float a0 = 0.f, a1 = 0.f, a2 = 0.f, a3 = 0.f;
#pragma unroll
      for (int i = 0; i < 8; ++i) {
#pragma unroll
        for (int c = 0; c < 4; ++c) {
          const float avc = av[i][c];
          a0 = fmaf(w1r[0][i][c], avc, a0);
          a1 = fmaf(w1r[1][i][c], avc, a1);
          a2 = fmaf(w1r[2][i][c], avc, a2);
          a3 = fmaf(w1r[3][i][c], avc, a3);
        }
      }
      f4 pv = {a0, a1, a2, a3};
      *(f4*)&P[kh][lf][oq * 4] = pv;
    }
  }
  __syncthreads();

  // ---- combine1 -> h1 = relu(P0 + P1 + b1) ----
  for (int e = tid; e < 33 * 16; e += 256) {
    const int lf = e >> 4, q = e & 15;
    f4 p0 = *(const f4*)&P[0][lf][q * 4];
    f4 p1 = *(const f4*)&P[1][lf][q * 4];
    f4 bq = *(const f4*)&bb1[q * 4];
    f4 s = p0 + p1 + bq;
#pragma unroll
    for (int c = 0; c < 4; ++c) s[c] = fmaxf(s[c], 0.f);
    *(f4*)&h1loc[lf * 68 + q * 4] = s;
  }
  __syncthreads();

  // ---- compute2 thread mapping: (oq2, kh2, lfp2) ----
  const int oq2  = tid & 7;         // outputs oq2*4..oq2*4+3
  const int kh2  = (tid >> 3) & 1;  // k half
  const int lfp2 = tid >> 4;        // 0..15; covers lf = lfp2 + 16m

  // Memory clobber: keep W2 loads from being hoisted above compute1 (would
  // make w1r+w2r simultaneously live -> spills).
  asm volatile("" ::: "memory");
  f4 w2r[4][8];
#pragma unroll
  for (int r = 0; r < 4; ++r)
#pragma unroll
    for (int i = 0; i < 8; ++i)
      w2r[r][i] = *(const f4*)&W2[(size_t)(oq2 * 4 + r) * 64 + kh2 * 32 + 4 * i];

#pragma unroll
  for (int m = 0; m < 3; ++m) {
    const int lf = lfp2 + 16 * m;
    if (lf < 33) {
      const f4* hr = (const f4*)&h1loc[lf * 68 + kh2 * 32];
      f4 hv[8];
#pragma unroll
      for (int i = 0; i < 8; ++i) hv[i] = hr[i];
      float a0 = 0.f, a1 = 0.f, a2 = 0.f, a3 = 0.f;
#pragma unroll
      for (int i = 0; i < 8; ++i) {
#pragma unroll
        for (int c = 0; c < 4; ++c) {
          const float hvc = hv[i][c];
          a0 = fmaf(w2r[0][i][c], hvc, a0);
          a1 = fmaf(w2r[1][i][c], hvc, a1);
          a2 = fmaf(w2r[2][i][c], hvc, a2);
          a3 = fmaf(w2r[3][i][c], hvc, a3);
        }
      }
      f4 pv = {a0, a1, a2, a3};
      *(f4*)&P2[kh2][lf][oq2 * 4] = pv;
    }
  }
  __syncthreads();

  // ---- combine2 -> y = P0 + P1 + b2 ----
  for (int e = tid; e < 33 * 8; e += 256) {
    const int lf = e >> 3, q = e & 7;
    f4 p0 = *(const f4*)&P2[0][lf][q * 4];
    f4 p1 = *(const f4*)&P2[1][lf][q * 4];
    f4 bq = *(const f4*)&bb2[q * 4];
    f4 s = p0 + p1 + bq;
    *(f4*)&yloc[lf * 32 + q * 4] = s;
  }
  __syncthreads();

  // overlap-add: sample s gets y[f1][s%16] (if f1 valid) + y[f1-1][s%16+16]
  const int s0 = f0 * 16 + 16;
  const int s1 = min(s0 + 512, Tn);
  for (int s = s0 + tid; s < s1; s += 256) {
    int f1  = s >> 4;
    int o1  = s & 15;
    int lf1 = f1 - f0;                       // in [1, 32]
    float v = yloc[(lf1 - 1) * 32 + o1 + 16];
    if (lf1 < nf) v += yloc[lf1 * 32 + o1];
    out[(size_t)b * Tn + s] = v;
  }
  if (fb == 0 && tid < 16) out[(size_t)b * Tn + tid] = yloc[tid];
}

// ---------------------------------------------------------------------------
extern "C" void kernel_launch(void* const* d_in, const int* in_sizes, int n_in,
                              void* d_out, int out_size, void* d_ws, size_t ws_size,
                              hipStream_t stream) {
  const float* x    = (const float*)d_in[0];
  const float* W_ih = (const float*)d_in[1];
  const float* W_hh = (const float*)d_in[2];
  const float* b_ih = (const float*)d_in[3];
  const float* b_hh = (const float*)d_in[4];
  const float* W_cs = (const float*)d_in[5];
  const float* b_cs = (const float*)d_in[6];
  const float* W1   = (const float*)d_in[7];
  const float* b1   = (const float*)d_in[8];
  const float* W2   = (const float*)d_in[9];
  const float* b2   = (const float*)d_in[10];
  float* out = (float*)d_out;

  float* GI = (float*)d_ws;                        // 128*999*192 fp32 = 98.2MB
  float* hs = GI + (size_t)Bn * NSn * G3n;         // 128*999*64  fp32 = 32.7MB
  float* cs = GI;                                  // reuse GI (dead after gru)

  gi_kernel<<<dim3(32, Bn), 192, 0, stream>>>(x, W_ih, b_ih, GI);
  gru_kernel<<<Bn, 64, 0, stream>>>(GI, W_hh, b_hh, hs);
  cs_kernel<<<dim3(32, Bn), 256, 0, stream>>>(hs, W_cs, b_cs, cs);
  out_kernel<<<dim3(94, Bn), 256, 0, stream>>>(x, cs, W1, b1, W2, b2, out);
}

// Round 4
// 771.576 us; speedup vs baseline: 1.6695x; 1.6695x over previous
//
#include <hip/hip_runtime.h>

// Problem constants
constexpr int Bn  = 128;
constexpr int Tn  = 48000;
constexpr int NFn = 2999;   // fast frames
constexpr int NSn = 999;    // slow frames
constexpr int G3n = 192;    // 3*GH
constexpr int GHn = 64;

typedef float f2 __attribute__((ext_vector_type(2)));
typedef float f4 __attribute__((ext_vector_type(4)));

// ---------------------------------------------------------------------------
// Kernel 1: GI[b, t, j] = b_ih[j] + sum_{k<96} x[b, t*48+k] * W_ih[j, k]
// (unchanged — known-good, no spills)
// ---------------------------------------------------------------------------
__global__ __launch_bounds__(192) void gi_kernel(const float* __restrict__ x,
                                                 const float* __restrict__ W_ih,
                                                 const float* __restrict__ b_ih,
                                                 float* __restrict__ GI) {
  __shared__ __align__(16) float WT[48 * 196];   // [k][j] padded stride 196
  __shared__ float xs[1584];                     // 31*48+96 samples
  const int tile = blockIdx.x;        // 0..31
  const int b    = blockIdx.y;        // 0..127
  const int t0   = tile * 32;
  const int nt   = min(32, NSn - t0); // 32 or 7 (last tile)
  const int tid  = threadIdx.x;

  const int span = (nt - 1) * 48 + 96;
  for (int i = tid; i < 1584; i += 192)
    xs[i] = (i < span) ? x[(size_t)b * Tn + t0 * 48 + i] : 0.0f;

  const int jq = tid % 48;   // j-quad index
  const int tg = tid / 48;   // t-group (0..3)
  const int j0 = jq * 4;

  float acc[8][4];
#pragma unroll
  for (int u = 0; u < 8; ++u)
#pragma unroll
    for (int jj = 0; jj < 4; ++jj) acc[u][jj] = b_ih[j0 + jj];

  for (int half = 0; half < 2; ++half) {
    __syncthreads();
    for (int e = tid; e < 192 * 48; e += 192) {
      int j = e / 48, k = e % 48;
      WT[k * 196 + j] = W_ih[j * 96 + half * 48 + k];
    }
    __syncthreads();
    for (int k = 0; k < 48; ++k) {
      float4 w = *(const float4*)&WT[k * 196 + j0];
#pragma unroll
      for (int u = 0; u < 8; ++u) {
        float xv = xs[(tg * 8 + u) * 48 + half * 48 + k];
        acc[u][0] = fmaf(xv, w.x, acc[u][0]);
        acc[u][1] = fmaf(xv, w.y, acc[u][1]);
        acc[u][2] = fmaf(xv, w.z, acc[u][2]);
        acc[u][3] = fmaf(xv, w.w, acc[u][3]);
      }
    }
  }

#pragma unroll
  for (int u = 0; u < 8; ++u) {
    int tl = tg * 8 + u;
    if (tl < nt) {
      float4 st = make_float4(acc[u][0], acc[u][1], acc[u][2], acc[u][3]);
      *(float4*)&GI[(size_t)(b * NSn + t0 + tl) * G3n + j0] = st;
    }
  }
}

// ---------------------------------------------------------------------------
// GRU body (round-0 proven version, 485us). Shared by standalone fallback
// kernel and the fat kernel's gru path.
// ---------------------------------------------------------------------------
__device__ __forceinline__ float fsigmoid(float v) {
  return __fdividef(1.0f, 1.0f + __expf(-v));
}
__device__ __forceinline__ float ftanh_f(float v) {
  return 1.0f - __fdividef(2.0f, __expf(2.0f * v) + 1.0f);
}

__device__ __forceinline__ void gru_body(const float* __restrict__ GI,
                                         const float* __restrict__ W_hh,
                                         const float* __restrict__ b_hh,
                                         float* __restrict__ hs,
                                         float* hbuf, int b, int j) {
  f2 wr2[32], wz2[32], wn2[32];
  const f2* Wr = (const f2*)(W_hh + (size_t)j * 64);
  const f2* Wz = (const f2*)(W_hh + (size_t)(j + 64) * 64);
  const f2* Wn = (const f2*)(W_hh + (size_t)(j + 128) * 64);
#pragma unroll
  for (int q = 0; q < 32; ++q) { wr2[q] = Wr[q]; wz2[q] = Wz[q]; wn2[q] = Wn[q]; }
  // Opaque to the compiler => cannot re-load from memory inside the loop.
#pragma unroll
  for (int q = 0; q < 32; ++q) {
    asm volatile("" : "+v"(wr2[q]));
    asm volatile("" : "+v"(wz2[q]));
    asm volatile("" : "+v"(wn2[q]));
  }
  const float br = b_hh[j], bz = b_hh[j + 64], bn = b_hh[j + 128];

  hbuf[j] = 0.0f;
  float hj = 0.0f;
  __builtin_amdgcn_wave_barrier();

  const float* gp = GI + (size_t)b * NSn * G3n;
  float* hsp = hs + (size_t)b * NSn * GHn;

  // distance-2 prefetch ring
  float pr0, pr1, pr2, pz0, pz1, pz2, pn0, pn1, pn2;
  pr0 = gp[0 * G3n + j];       pz0 = gp[0 * G3n + 64 + j];  pn0 = gp[0 * G3n + 128 + j];
  pr1 = gp[1 * G3n + j];       pz1 = gp[1 * G3n + 64 + j];  pn1 = gp[1 * G3n + 128 + j];

  for (int t = 0; t < NSn; ++t) {
    const size_t off = (size_t)min(t + 2, NSn - 1) * G3n;
    pr2 = gp[off + j];
    pz2 = gp[off + 64 + j];
    pn2 = gp[off + 128 + j];

    const f2* h2 = (const f2*)hbuf;
    f2 ar0 = {0.f, 0.f}, ar1 = {0.f, 0.f}, ar2 = {0.f, 0.f}, ar3 = {0.f, 0.f};
    f2 az0 = {0.f, 0.f}, az1 = {0.f, 0.f}, az2 = {0.f, 0.f}, az3 = {0.f, 0.f};
    f2 an0 = {0.f, 0.f}, an1 = {0.f, 0.f}, an2 = {0.f, 0.f}, an3 = {0.f, 0.f};
#pragma unroll
    for (int q = 0; q < 8; ++q) {
      f2 h0 = h2[q * 4 + 0], h1 = h2[q * 4 + 1], h2v = h2[q * 4 + 2], h3 = h2[q * 4 + 3];
      ar0 += wr2[q * 4 + 0] * h0; ar1 += wr2[q * 4 + 1] * h1;
      ar2 += wr2[q * 4 + 2] * h2v; ar3 += wr2[q * 4 + 3] * h3;
      az0 += wz2[q * 4 + 0] * h0; az1 += wz2[q * 4 + 1] * h1;
      az2 += wz2[q * 4 + 2] * h2v; az3 += wz2[q * 4 + 3] * h3;
      an0 += wn2[q * 4 + 0] * h0; an1 += wn2[q * 4 + 1] * h1;
      an2 += wn2[q * 4 + 2] * h2v; an3 += wn2[q * 4 + 3] * h3;
    }
    f2 sr = (ar0 + ar1) + (ar2 + ar3);
    f2 sz = (az0 + az1) + (az2 + az3);
    f2 sn = (an0 + an1) + (an2 + an3);

    float r = fsigmoid(pr0 + br + sr.x + sr.y);
    float z = fsigmoid(pz0 + bz + sz.x + sz.y);
    float n = ftanh_f(fmaf(r, bn + sn.x + sn.y, pn0));
    float hn = fmaf(z, hj - n, n);          // (1-z)*n + z*h

    __builtin_amdgcn_wave_barrier();
    hbuf[j] = hn;
    __builtin_amdgcn_wave_barrier();
    hj = hn;
    hsp[(size_t)t * GHn + j] = hn;

    pr0 = pr1; pr1 = pr2;
    pz0 = pz1; pz1 = pz2;
    pn0 = pn1; pn1 = pn2;
  }
}

// Standalone gru (fallback path) — round-0 exact behavior.
__global__ __attribute__((amdgpu_flat_work_group_size(64, 64),
                          amdgpu_waves_per_eu(1, 1),
                          amdgpu_num_vgpr(256)))
void gru_kernel(const float* __restrict__ GI,
                const float* __restrict__ W_hh,
                const float* __restrict__ b_hh,
                float* __restrict__ hs) {
  __shared__ __align__(16) float hbuf[64];
  gru_body(GI, W_hh, b_hh, hs, hbuf, blockIdx.x, threadIdx.x);
}

// ---------------------------------------------------------------------------
// FAT kernel: blocks [0,128) run the gru (the 485us serial pole, which uses
// only 128 of 1024 SIMDs — VALUBusy 7.4% measured); blocks [128, 128+3072)
// concurrently compute U[b,f,o] = b1[o] + fast_frame(b,f) . W1[o, 0:32]
// (the gru-independent 2/3 of the old out_kernel's GEMM work, ~786M FMA,
// ~35us spread over the ~896 idle SIMDs -> fully hidden under the gru).
// Paths are block-uniform and fully independent (disjoint reads/writes),
// so no ordering/coherence assumption is made.
// ---------------------------------------------------------------------------
constexpr int UCHUNK = 125;
constexpr int NCH    = 24;            // 24*125 = 3000 >= 2999

__global__ __attribute__((amdgpu_flat_work_group_size(64, 64),
                          amdgpu_waves_per_eu(1, 1),
                          amdgpu_num_vgpr(256)))
void fat_kernel(const float* __restrict__ GI,
                const float* __restrict__ W_hh,
                const float* __restrict__ b_hh,
                float* __restrict__ hs,
                const float* __restrict__ x,
                const float* __restrict__ W1,
                const float* __restrict__ b1,
                float* __restrict__ U) {
  __shared__ __align__(16) float hbuf[64];
  __shared__ __align__(16) float xs[UCHUNK * 16 + 16];   // 2016
  const int tid = threadIdx.x;

  if (blockIdx.x < Bn) {
    gru_body(GI, W_hh, b_hh, hs, hbuf, blockIdx.x, tid);
    return;
  }

  // ---- U path ----
  const int ub = blockIdx.x - Bn;       // 0 .. 128*24-1
  const int b  = ub / NCH;
  const int ch = ub % NCH;
  const int fA = ch * UCHUNK;
  const int fE = min(fA + UCHUNK, NFn);
  const int o  = tid;                    // 0..63 output channel

  const int nsamp = (fE - fA - 1) * 16 + 32;   // <= 2016; last: ends at 48000
  for (int i = tid; i < nsamp; i += 64)
    xs[i] = x[(size_t)b * Tn + fA * 16 + i];

  f4 w1f[8];
#pragma unroll
  for (int i = 0; i < 8; ++i)
    w1f[i] = *(const f4*)&W1[(size_t)o * 64 + 4 * i];
  const float bo = b1[o];
  __syncthreads();

  float* Up = U + ((size_t)b * NFn) * GHn + o;
  for (int f = fA; f < fE; ++f) {
    const f4* xq = (const f4*)&xs[(f - fA) * 16];   // 64B-aligned
    float a0 = bo, a1 = 0.f, a2 = 0.f, a3 = 0.f;
#pragma unroll
    for (int i = 0; i < 8; ++i) {
      f4 xv = xq[i];                                // uniform -> LDS broadcast
      a0 = fmaf(xv[0], w1f[i][0], a0);
      a1 = fmaf(xv[1], w1f[i][1], a1);
      a2 = fmaf(xv[2], w1f[i][2], a2);
      a3 = fmaf(xv[3], w1f[i][3], a3);
    }
    Up[(size_t)f * GHn] = (a0 + a1) + (a2 + a3);
  }
}

// ---------------------------------------------------------------------------
// Kernel 2b (fast path): d[b,ts,o] = sum_i c[b,ts,i] * W1[o, 32+i],
// c[b,ts,i] = b_cs[i] + sum_k hs[b,ts,k] * W_cs[i,k].
// Chained small GEMMs, both staged in LDS (proven-cheap broadcast pattern).
// ---------------------------------------------------------------------------
__global__ __launch_bounds__(256) void d_kernel(const float* __restrict__ hs,
                                                const float* __restrict__ W_cs,
                                                const float* __restrict__ b_cs,
                                                const float* __restrict__ W1,
                                                float* __restrict__ d) {
  __shared__ __align__(16) float WcT[64 * 36];   // [k][i] stride 36
  __shared__ __align__(16) float W1cT[32 * 68];  // [i][o] stride 68
  __shared__ __align__(16) float hsl[32 * 65];   // [t][k] stride 65
  __shared__ __align__(16) float cloc[32 * 36];  // [t][i] stride 36
  __shared__ __align__(16) float bcs[32];
  const int tile = blockIdx.x;   // 0..31
  const int b    = blockIdx.y;
  const int t0   = tile * 32;
  const int nt   = min(32, NSn - t0);
  const int tid  = threadIdx.x;

  for (int e = tid; e < 32 * 64; e += 256) {
    int i = e >> 6, k = e & 63;
    WcT[k * 36 + i] = W_cs[e];
  }
  for (int e = tid; e < 64 * 32; e += 256) {
    int o = e >> 5, i = e & 31;
    W1cT[i * 68 + o] = W1[(size_t)o * 64 + 32 + i];
  }
  for (int e = tid; e < nt * 64; e += 256) {
    int t = e >> 6, k = e & 63;
    hsl[t * 65 + k] = hs[((size_t)b * NSn + t0 + t) * GHn + k];
  }
  if (tid < 32) bcs[tid] = b_cs[tid];
  __syncthreads();

  // phase 1: c tile (32 ts x 32 i), thread = (t, iq)
  {
    const int iq = tid & 7;
    const int t  = tid >> 3;
    if (t < nt) {
      float4 acc = *(const float4*)&bcs[iq * 4];
      const float* hr = &hsl[t * 65];
#pragma unroll 4
      for (int k = 0; k < 64; ++k) {
        float hv = hr[k];
        float4 w = *(const float4*)&WcT[k * 36 + iq * 4];
        acc.x = fmaf(w.x, hv, acc.x);
        acc.y = fmaf(w.y, hv, acc.y);
        acc.z = fmaf(w.z, hv, acc.z);
        acc.w = fmaf(w.w, hv, acc.w);
      }
      *(float4*)&cloc[t * 36 + iq * 4] = acc;
    }
  }
  __syncthreads();

  // phase 2: d tile (32 ts x 64 o), thread = (t, oq), two passes
  for (int it = tid; it < 32 * 16; it += 256) {
    const int oq = it & 15;
    const int t  = it >> 4;
    if (t < nt) {
      float a0 = 0.f, a1 = 0.f, a2 = 0.f, a3 = 0.f;
      const float* cr = &cloc[t * 36];
#pragma unroll 4
      for (int i = 0; i < 32; ++i) {
        float cv = cr[i];
        float4 w = *(const float4*)&W1cT[i * 68 + oq * 4];
        a0 = fmaf(w.x, cv, a0);
        a1 = fmaf(w.y, cv, a1);
        a2 = fmaf(w.z, cv, a2);
        a3 = fmaf(w.w, cv, a3);
      }
      float4 st = make_float4(a0, a1, a2, a3);
      *(float4*)&d[((size_t)b * NSn + t0 + t) * GHn + oq * 4] = st;
    }
  }
}

// ---------------------------------------------------------------------------
// Kernel 2b (fallback): old cs_kernel (32-wide c output).
// ---------------------------------------------------------------------------
__global__ __launch_bounds__(256) void cs_kernel(const float* __restrict__ hs,
                                                 const float* __restrict__ W_cs,
                                                 const float* __restrict__ b_cs,
                                                 float* __restrict__ cs) {
  __shared__ __align__(16) float WcT[64 * 36];  // [k][i] stride 36
  __shared__ __align__(16) float hsl[32 * 65];  // [t][k] stride 65
  __shared__ __align__(16) float bcs[32];
  const int tile = blockIdx.x;   // 0..31
  const int b    = blockIdx.y;
  const int t0   = tile * 32;
  const int nt   = min(32, NSn - t0);
  const int tid  = threadIdx.x;

  for (int e = tid; e < 32 * 64; e += 256) {
    int i = e >> 6, k = e & 63;
    WcT[k * 36 + i] = W_cs[e];
  }
  for (int e = tid; e < nt * 64; e += 256) {
    int t = e >> 6, k = e & 63;
    hsl[t * 65 + k] = hs[((size_t)b * NSn + t0 + t) * GHn + k];
  }
  if (tid < 32) bcs[tid] = b_cs[tid];
  __syncthreads();

  const int oq = tid & 7;    // output quad 0..7
  const int t  = tid >> 3;   // 0..31
  if (t < nt) {
    float4 acc = *(const float4*)&bcs[oq * 4];
    const float* hr = &hsl[t * 65];
#pragma unroll 4
    for (int k = 0; k < 64; ++k) {
      float hv = hr[k];
      float4 w = *(const float4*)&WcT[k * 36 + oq * 4];
      acc.x = fmaf(w.x, hv, acc.x);
      acc.y = fmaf(w.y, hv, acc.y);
      acc.z = fmaf(w.z, hv, acc.z);
      acc.w = fmaf(w.w, hv, acc.w);
    }
    *(float4*)&cs[((size_t)b * NSn + t0 + t) * 32 + oq * 4] = acc;
  }
}

// ---------------------------------------------------------------------------
// Kernel 3 (fast path): h = relu(U + d[ts]), y = h@W2^T + b2, overlap-add.
// U read coalesced from global (1KB/wave-instr); only the small W2 GEMM
// remains in the proven LDS-broadcast form (~1/3 of the old out's DS work).
// ---------------------------------------------------------------------------
__global__ __launch_bounds__(256) void out2_kernel(const float* __restrict__ U,
                                                   const float* __restrict__ d,
                                                   const float* __restrict__ W2,
                                                   const float* __restrict__ b2,
                                                   float* __restrict__ out) {
  __shared__ __align__(16) float h1loc[33 * 68]; // [lf][o] stride 68
  __shared__ __align__(16) float W2T[64 * 36];   // [k][o] stride 36
  __shared__ __align__(16) float yloc[33 * 32];
  __shared__ __align__(16) float dloc[12][68];   // staged d rows
  __shared__ __align__(16) float bb2[32];

  const int fb  = blockIdx.x;
  const int b   = blockIdx.y;
  const int f0  = fb * 32;
  const int nf  = min(33, NFn - f0);
  const int tid = threadIdx.x;
  const int ts0 = max(f0 / 3 - 1, 0);

  for (int e = tid; e < 32 * 64; e += 256) {
    int o = e >> 6, k = e & 63;
    W2T[k * 36 + o] = W2[e];
  }
  if (tid < 32) bb2[tid] = b2[tid];
  for (int e = tid; e < 12 * 64; e += 256) {
    int ti = e >> 6, o = e & 63;
    int ts = min(ts0 + ti, NSn - 1);
    dloc[ti][o] = d[((size_t)b * NSn + ts) * GHn + o];
  }
  __syncthreads();

  // h = relu(U + d): thread = (lf, oq), ~2 passes; coalesced U quads.
  for (int it = tid; it < 33 * 16; it += 256) {
    const int lf = it >> 4, oq = it & 15;
    const int f  = f0 + lf;
    f4 s = {0.f, 0.f, 0.f, 0.f};
    if (f < NFn) {
      f4 u  = *(const f4*)&U[((size_t)b * NFn + f) * GHn + oq * 4];
      const int ti = max(f / 3 - 1, 0) - ts0;     // in [0, 11]
      f4 dv = *(const f4*)&dloc[ti][oq * 4];
      s = u + dv;
#pragma unroll
      for (int c = 0; c < 4; ++c) s[c] = fmaxf(s[c], 0.f);
    }
    *(f4*)&h1loc[lf * 68 + oq * 4] = s;
  }
  __syncthreads();

  // y = W2 @ h + b2: thread = (lf, oq), ~1 pass (proven broadcast GEMM)
  for (int it = tid; it < 33 * 8; it += 256) {
    const int lf = it >> 3, oq = it & 7;
    float4 acc = *(const float4*)&bb2[oq * 4];
    const float* hr = &h1loc[lf * 68];
#pragma unroll 4
    for (int k = 0; k < 64; ++k) {
      float hv = hr[k];
      float4 w = *(const float4*)&W2T[k * 36 + oq * 4];
      acc.x = fmaf(w.x, hv, acc.x);
      acc.y = fmaf(w.y, hv, acc.y);
      acc.z = fmaf(w.z, hv, acc.z);
      acc.w = fmaf(w.w, hv, acc.w);
    }
    *(float4*)&yloc[lf * 32 + oq * 4] = acc;
  }
  __syncthreads();

  // overlap-add (unchanged, proven)
  const int s0 = f0 * 16 + 16;
  const int s1 = min(s0 + 512, Tn);
  for (int s = s0 + tid; s < s1; s += 256) {
    int f1  = s >> 4;
    int o1  = s & 15;
    int lf1 = f1 - f0;                       // in [1, 32]
    float v = yloc[(lf1 - 1) * 32 + o1 + 16];
    if (lf1 < nf) v += yloc[lf1 * 32 + o1];
    out[(size_t)b * Tn + s] = v;
  }
  if (fb == 0 && tid < 16) out[(size_t)b * Tn + tid] = yloc[tid];
}

// ---------------------------------------------------------------------------
// Kernel 3 (fallback): round-0 out_kernel (LDS-broadcast GEMMs, ~210us).
// ---------------------------------------------------------------------------
__global__ __launch_bounds__(256) void out_kernel(const float* __restrict__ x,
                                                  const float* __restrict__ cs,
                                                  const float* __restrict__ W1,
                                                  const float* __restrict__ b1,
                                                  const float* __restrict__ W2,
                                                  const float* __restrict__ b2,
                                                  float* __restrict__ out) {
  __shared__ __align__(16) float A[33 * 65];     // [lf][k], k<32 = x, k>=32 = c
  __shared__ __align__(16) float W1T[64 * 68];   // [k][o] stride 68
  __shared__ __align__(16) float W2T[64 * 36];   // [k][o] stride 36
  __shared__ __align__(16) float h1loc[33 * 65]; // [lf][o] stride 65
  __shared__ __align__(16) float yloc[33 * 32];
  __shared__ __align__(16) float bb1[64];
  __shared__ __align__(16) float bb2[32];

  const int fb  = blockIdx.x;
  const int b   = blockIdx.y;
  const int f0  = fb * 32;
  const int nf  = min(33, NFn - f0);
  const int tid = threadIdx.x;

  for (int e = tid; e < 64 * 64; e += 256) {
    int o = e >> 6, k = e & 63;
    W1T[k * 68 + o] = W1[e];
  }
  for (int e = tid; e < 32 * 64; e += 256) {
    int o = e >> 6, k = e & 63;
    W2T[k * 36 + o] = W2[e];
  }
  if (tid < 64) bb1[tid] = b1[tid];
  if (tid < 32) bb2[tid] = b2[tid];

  for (int e = tid; e < 33 * 32; e += 256) {
    int lf = e >> 5, k = e & 31;
    int g = (f0 + lf) * 16 + k;
    A[lf * 65 + k] = (lf < nf && g < Tn) ? x[(size_t)b * Tn + g] : 0.0f;
  }
  for (int e = tid; e < 33 * 32; e += 256) {
    int lf = e >> 5, k = e & 31;
    int ts = max((f0 + lf) / 3 - 1, 0);
    A[lf * 65 + 32 + k] = (lf < nf) ? cs[((size_t)b * NSn + ts) * 32 + k] : 0.0f;
  }
  __syncthreads();

  for (int it = tid; it < 33 * 16; it += 256) {
    int lf = it >> 4, oq = it & 15;
    float4 acc = *(const float4*)&bb1[oq * 4];
    const float* ar = &A[lf * 65];
#pragma unroll 4
    for (int k = 0; k < 64; ++k) {
      float av = ar[k];
      float4 w = *(const float4*)&W1T[k * 68 + oq * 4];
      acc.x = fmaf(w.x, av, acc.x);
      acc.y = fmaf(w.y, av, acc.y);
      acc.z = fmaf(w.z, av, acc.z);
      acc.w = fmaf(w.w, av, acc.w);
    }
    acc.x = fmaxf(acc.x, 0.0f); acc.y = fmaxf(acc.y, 0.0f);
    acc.z = fmaxf(acc.z, 0.0f); acc.w = fmaxf(acc.w, 0.0f);
    *(float4*)&h1loc[lf * 65 + oq * 4] = acc;
  }
  __syncthreads();

  for (int it = tid; it < 33 * 8; it += 256) {
    int lf = it >> 3, oq = it & 7;
    float4 acc = *(const float4*)&bb2[oq * 4];
    const float* hr = &h1loc[lf * 65];
#pragma unroll 4
    for (int k = 0; k < 64; ++k) {
      float hv = hr[k];
      float4 w = *(const float4*)&W2T[k * 36 + oq * 4];
      acc.x = fmaf(w.x, hv, acc.x);
      acc.y = fmaf(w.y, hv, acc.y);
      acc.z = fmaf(w.z, hv, acc.z);
      acc.w = fmaf(w.w, hv, acc.w);
    }
    *(float4*)&yloc[lf * 32 + oq * 4] = acc;
  }
  __syncthreads();

  const int s0 = f0 * 16 + 16;
  const int s1 = min(s0 + 512, Tn);
  for (int s = s0 + tid; s < s1; s += 256) {
    int f1  = s >> 4;
    int o1  = s & 15;
    int lf1 = f1 - f0;                       // in [1, 32]
    float v = yloc[(lf1 - 1) * 32 + o1 + 16];
    if (lf1 < nf) v += yloc[lf1 * 32 + o1];
    out[(size_t)b * Tn + s] = v;
  }
  if (fb == 0 && tid < 16) out[(size_t)b * Tn + tid] = yloc[tid];
}

// ---------------------------------------------------------------------------
extern "C" void kernel_launch(void* const* d_in, const int* in_sizes, int n_in,
                              void* d_out, int out_size, void* d_ws, size_t ws_size,
                              hipStream_t stream) {
  const float* x    = (const float*)d_in[0];
  const float* W_ih = (const float*)d_in[1];
  const float* W_hh = (const float*)d_in[2];
  const float* b_ih = (const float*)d_in[3];
  const float* b_hh = (const float*)d_in[4];
  const float* W_cs = (const float*)d_in[5];
  const float* b_cs = (const float*)d_in[6];
  const float* W1   = (const float*)d_in[7];
  const float* b1   = (const float*)d_in[8];
  const float* W2   = (const float*)d_in[9];
  const float* b2   = (const float*)d_in[10];
  float* out = (float*)d_out;

  const size_t giN = (size_t)Bn * NSn * G3n;   // 24,551,424 floats (98.2 MB)
  const size_t hsN = (size_t)Bn * NSn * GHn;   //  8,183,808 floats (32.7 MB)
  const size_t uN  = (size_t)Bn * NFn * GHn;   // 24,567,808 floats (98.3 MB)

  float* GI = (float*)d_ws;
  float* hs = GI + giN;

  gi_kernel<<<dim3(32, Bn), 192, 0, stream>>>(x, W_ih, b_ih, GI);

  if (ws_size >= (giN + hsN + uN) * sizeof(float)) {
    // Fast path: gru overlapped with U precompute; d = cond-half of W1 GEMM.
    float* U = hs + hsN;
    float* d = GI;                             // GI dead after fat_kernel
    fat_kernel<<<Bn + Bn * NCH, 64, 0, stream>>>(GI, W_hh, b_hh, hs,
                                                 x, W1, b1, U);
    d_kernel<<<dim3(32, Bn), 256, 0, stream>>>(hs, W_cs, b_cs, W1, d);
    out2_kernel<<<dim3(94, Bn), 256, 0, stream>>>(U, d, W2, b2, out);
  } else {
    // Fallback: proven round-0 pipeline.
    float* cs = GI;                            // reuse GI (dead after gru)
    gru_kernel<<<Bn, 64, 0, stream>>>(GI, W_hh, b_hh, hs);
    cs_kernel<<<dim3(32, Bn), 256, 0, stream>>>(hs, W_cs, b_cs, cs);
    out_kernel<<<dim3(94, Bn), 256, 0, stream>>>(x, cs, W1, b1, W2, b2, out);
  }
}